// Round 11
// baseline (703.988 us; speedup 1.0000x reference)
//
#include <hip/hip_runtime.h>

#define BATCH 8
#define LFRM  6
#define NP    2048
#define MP    1024
#define CIN   64
#define MIDC  128
#define OUTC  256
#define TKM   384
#define KNN   32
#define RAD2  0.25f

#define FPS_BLOCKS (BATCH * LFRM)
#define WT_BLOCKS  ((OUTC * TKM) / (256 * 4))   // 96
#define FT_BLOCKS  (BATCH * LFRM * (NP / 64))
#define WFS 132   // wfT row stride: 16B-aligned rows (528B) for b128 reads

typedef float f2 __attribute__((ext_vector_type(2)));
typedef float f32x4 __attribute__((ext_vector_type(4)));
typedef _Float16 f16x8 __attribute__((ext_vector_type(8)));
typedef _Float16 f16x4 __attribute__((ext_vector_type(4)));

// LDS union: fps needs 32.2KB; ftrans needs ~51.3KB.
union SharedU {
  struct {
    float4 pts[NP];                    // 32 KB, [x,y,z,pad]
    float4 wslot[2][4];                // parity-buffered {dist, x, y, z}
  } fps;
  struct {
    float ftile[CIN][64];              // 16 KB
    float wfT[CIN][WFS];               // 33 KB  [c][o], 16B-aligned rows
    float xt[64], yt[64], zt[64];      // point coords of this tile
    float wdl[MIDC * 3];               // w_d staged
  } ft;
};

__device__ __forceinline__ uint64_t kmax64(uint64_t a, uint64_t b) {
  return a > b ? a : b;
}
template <int CTRL>
__device__ __forceinline__ uint64_t key_dpp(uint64_t k) {
  int lo = __builtin_amdgcn_update_dpp((int)(uint32_t)k, (int)(uint32_t)k,
                                       CTRL, 0xF, 0xF, false);
  int hi = __builtin_amdgcn_update_dpp((int)(uint32_t)(k >> 32),
                                       (int)(uint32_t)(k >> 32),
                                       CTRL, 0xF, 0xF, false);
  return ((uint64_t)(uint32_t)hi << 32) | (uint32_t)lo;
}

__device__ __forceinline__ f16x4 h4max(f16x4 a, f16x4 b) {
  f16x4 r;
  r[0] = a[0] > b[0] ? a[0] : b[0];
  r[1] = a[1] > b[1] ? a[1] : b[1];
  r[2] = a[2] > b[2] ? a[2] : b[2];
  r[3] = a[3] > b[3] ? a[3] : b[3];
  return r;
}

// ---------------------------------------------------------------------------
// FPS: r8 base + coord-publish. Per wave: u64-key DPP reduce (ror1..8 +
// bcast15 + bcast31 -> lane63), readlane63 broadcast; the unique winner lane
// (kl == skr; keys embed unique index) publishes float4{dist,x,y,z}. The
// cross-wave combine is 3 float compares -- strict '>' prefers the LOWER
// wave on ties, and wave wv owns indices [wv*512,(wv+1)*512), so this is
// exactly numpy first-occurrence argmax (tie -> smaller index). Removes the
// post-barrier u64 tree + dependent pts[wp] LDS read from the serial path.
// ---------------------------------------------------------------------------
__device__ __forceinline__ void fps_path(const float* __restrict__ xyzs,
                                         float* __restrict__ out_xyz,
                                         SharedU* sh) {
#pragma clang fp contract(off)
  const int bt = blockIdx.x;              // b*6 + frame
  const int tid = threadIdx.x;
  const int lane = tid & 63, wv = tid >> 6;
  const float* src = xyzs + (size_t)bt * NP * 3;

  for (int q = tid; q < NP; q += 256)
    sh->fps.pts[q] = make_float4(src[q * 3 + 0], src[q * 3 + 1], src[q * 3 + 2], 0.f);
  __syncthreads();

  // wave wv owns slots [wv*8, wv*8+8); point p = slot*64 + lane
  f2 px[4], py[4], pz[4], dist[4];
#pragma unroll
  for (int u = 0; u < 4; ++u) {
    float4 a = sh->fps.pts[(wv * 8 + 2 * u) * 64 + lane];
    float4 b = sh->fps.pts[(wv * 8 + 2 * u + 1) * 64 + lane];
    px[u] = f2{a.x, b.x};
    py[u] = f2{a.y, b.y};
    pz[u] = f2{a.z, b.z};
    dist[u] = f2{1e10f, 1e10f};
  }

  float4 p0 = sh->fps.pts[0];
  float fx = p0.x, fy = p0.y, fz = p0.z;  // far = 0 initially
  float* dst = out_xyz + (size_t)bt * MP * 3;

  for (int it = 0; it < MP; ++it) {
    if (tid == 0) {                       // emit current far point
      dst[it * 3 + 0] = fx;
      dst[it * 3 + 1] = fy;
      dst[it * 3 + 2] = fz;
    }
    const f2 fx2 = {fx, fx}, fy2 = {fy, fy}, fz2 = {fz, fz};
    float bv = -1.0f;
    int bsu = 0;
#pragma unroll
    for (int u = 0; u < 4; ++u) {
      f2 dx = px[u] - fx2;
      f2 dy = py[u] - fy2;
      f2 dz = pz[u] - fz2;
      f2 m = dx * dx;                     // contract off: ((dx^2+dy^2)+dz^2)
      m = m + dy * dy;
      m = m + dz * dz;
      f2 nd = __builtin_elementwise_min(dist[u], m);
      dist[u] = nd;
      bool cx = nd.x > bv;                // first-occurrence: strict >
      bv = cx ? nd.x : bv;
      bsu = cx ? 2 * u : bsu;
      bool cy = nd.y > bv;
      bv = cy ? nd.y : bv;
      bsu = cy ? 2 * u + 1 : bsu;
    }
    const uint32_t p = (uint32_t)(((wv * 8 + bsu) << 6) | lane);
    const uint64_t kl = ((uint64_t)__float_as_uint(bv) << 32) | (uint32_t)(~p);
    uint64_t kr = kl;
    kr = kmax64(kr, key_dpp<0x121>(kr));  // row_ror:1
    kr = kmax64(kr, key_dpp<0x122>(kr));  // row_ror:2
    kr = kmax64(kr, key_dpp<0x124>(kr));  // row_ror:4
    kr = kmax64(kr, key_dpp<0x128>(kr));  // row_ror:8  -> row max
    kr = kmax64(kr, key_dpp<0x142>(kr));  // row_bcast15
    kr = kmax64(kr, key_dpp<0x143>(kr));  // row_bcast31: lane63 = wave max
    const uint32_t rlo = (uint32_t)__builtin_amdgcn_readlane((int)(uint32_t)kr, 63);
    const uint32_t rhi = (uint32_t)__builtin_amdgcn_readlane((int)(uint32_t)(kr >> 32), 63);
    const uint64_t skr = ((uint64_t)rhi << 32) | rlo;

    const int par = it & 1;
    if (kl == skr) {                      // unique winner lane of this wave
      float cx = px[0].x, cy = py[0].x, cz = pz[0].x;
      if (bsu == 1) { cx = px[0].y; cy = py[0].y; cz = pz[0].y; }
      if (bsu == 2) { cx = px[1].x; cy = py[1].x; cz = pz[1].x; }
      if (bsu == 3) { cx = px[1].y; cy = py[1].y; cz = pz[1].y; }
      if (bsu == 4) { cx = px[2].x; cy = py[2].x; cz = pz[2].x; }
      if (bsu == 5) { cx = px[2].y; cy = py[2].y; cz = pz[2].y; }
      if (bsu == 6) { cx = px[3].x; cy = py[3].x; cz = pz[3].x; }
      if (bsu == 7) { cx = px[3].y; cy = py[3].y; cz = pz[3].y; }
      sh->fps.wslot[par][wv] = make_float4(bv, cx, cy, cz);
    }
    __syncthreads();
    const float4 s0 = sh->fps.wslot[par][0];
    const float4 s1 = sh->fps.wslot[par][1];
    const float4 s2 = sh->fps.wslot[par][2];
    const float4 s3 = sh->fps.wslot[par][3];
    bool ca = s1.x > s0.x; float4 va = ca ? s1 : s0;  // tie -> lower wave
    bool cb = s3.x > s2.x; float4 vb = cb ? s3 : s2;
    bool cc = vb.x > va.x; float4 vw = cc ? vb : va;
    fx = vw.y; fy = vw.z; fz = vw.w;
  }
}

// ---------------------------------------------------------------------------
// wt: one-time fp16 conversion of w_t.
// ---------------------------------------------------------------------------
__device__ __forceinline__ void wt_path(const float* __restrict__ w_t,
                                        _Float16* __restrict__ wtH) {
  const int blk = blockIdx.x - FPS_BLOCKS;
  const int idx = (blk * 256 + (int)threadIdx.x) * 4;
  const float4 v = *(const float4*)&w_t[idx];
  f16x4 h;
  h[0] = (_Float16)v.x; h[1] = (_Float16)v.y;
  h[2] = (_Float16)v.z; h[3] = (_Float16)v.w;
  *(f16x4*)&wtH[idx] = h;
}

// ---------------------------------------------------------------------------
// ftrans: G[b,l,n,o] = sum_c w_f[o,c]*features[b,l,c,n] + w_d[o]·xyz[b,l,n]
// Register-blocked 4o x 8n per thread; fp16 G output (max is monotone).
// ---------------------------------------------------------------------------
__device__ __forceinline__ void ftrans_path(const float* __restrict__ features,
                                            const float* __restrict__ w_f,
                                            const float* __restrict__ w_d,
                                            const float* __restrict__ xyzs,
                                            _Float16* __restrict__ G,
                                            SharedU* sh) {
  const int blk = blockIdx.x - FPS_BLOCKS - WT_BLOCKS;
  const int ntile = blk & 31;             // N/64 tiles
  const int bl = blk >> 5;                // b*L + l
  const int tid = threadIdx.x;

  const float* fsrc = features + (size_t)bl * CIN * NP + (size_t)ntile * 64;
  for (int idx = tid; idx < CIN * 64; idx += 256) {
    int c = idx >> 6, n = idx & 63;
    sh->ft.ftile[c][n] = fsrc[(size_t)c * NP + n];
  }
  for (int idx = tid; idx < CIN * MIDC; idx += 256) {
    int c = idx & 63, o = idx >> 6;       // coalesced w_f row reads
    sh->ft.wfT[c][o] = w_f[o * CIN + c];
  }
  if (tid < 64) {
    const float* xs = xyzs + ((size_t)bl * NP + (size_t)ntile * 64 + tid) * 3;
    sh->ft.xt[tid] = xs[0];
    sh->ft.yt[tid] = xs[1];
    sh->ft.zt[tid] = xs[2];
  }
  for (int idx = tid; idx < MIDC * 3; idx += 256) sh->ft.wdl[idx] = w_d[idx];
  __syncthreads();

  const int op = tid & 31;                // o base = op*4 (coalesced stores)
  const int ng = tid >> 5;                // n base = ng*8 (broadcast ftile)
  const int ob = op * 4;
  const int nb = ng * 8;

  float acc[4][8];                        // all index loops fully unrolled
#pragma unroll
  for (int oo = 0; oo < 4; ++oo) {
    const float w0 = sh->ft.wdl[(ob + oo) * 3 + 0];
    const float w1 = sh->ft.wdl[(ob + oo) * 3 + 1];
    const float w2 = sh->ft.wdl[(ob + oo) * 3 + 2];
#pragma unroll
    for (int j = 0; j < 8; ++j)
      acc[oo][j] = w0 * sh->ft.xt[nb + j] + w1 * sh->ft.yt[nb + j] +
                   w2 * sh->ft.zt[nb + j];
  }

#pragma unroll 4
  for (int c = 0; c < CIN; ++c) {
    const float4 wq = *(const float4*)&sh->ft.wfT[c][ob];
    const float4 fA = *(const float4*)&sh->ft.ftile[c][nb];
    const float4 fB = *(const float4*)&sh->ft.ftile[c][nb + 4];
    const float wo[4] = {wq.x, wq.y, wq.z, wq.w};
    const float fv[8] = {fA.x, fA.y, fA.z, fA.w, fB.x, fB.y, fB.z, fB.w};
#pragma unroll
    for (int oo = 0; oo < 4; ++oo)
#pragma unroll
      for (int j = 0; j < 8; ++j)
        acc[oo][j] += wo[oo] * fv[j];
  }

  _Float16* dstp = G + ((size_t)bl * NP + (size_t)ntile * 64) * MIDC;
#pragma unroll
  for (int j = 0; j < 8; ++j) {
    f16x4 v;
    v[0] = (_Float16)acc[0][j]; v[1] = (_Float16)acc[1][j];
    v[2] = (_Float16)acc[2][j]; v[3] = (_Float16)acc[3][j];
    *(f16x4*)&dstp[(size_t)(nb + j) * MIDC + ob] = v;
  }
}

__global__ __launch_bounds__(256, 1) void fps_ftrans_kernel(
    const float* __restrict__ xyzs, const float* __restrict__ features,
    const float* __restrict__ w_f, const float* __restrict__ w_d,
    const float* __restrict__ w_t, float* __restrict__ out_xyz,
    _Float16* __restrict__ G, _Float16* __restrict__ wtH) {
  __shared__ SharedU sh;
  if (blockIdx.x < FPS_BLOCKS) {
    fps_path(xyzs, out_xyz, &sh);
    return;
  }
  if (blockIdx.x < FPS_BLOCKS + WT_BLOCKS) {
    wt_path(w_t, wtH);
    return;
  }
  ftrans_path(features, w_f, w_d, xyzs, G, &sh);
}

// ---------------------------------------------------------------------------
// pst_main: ball query + fp16 gathered max-pool of G + fp16 MFMA w_t GEMM.
// New: XCD-bijective block swizzle (1536 % 8 == 0): each XCD hosts the 6
// consecutive bt of one batch -> its 6 G-frames (3MB fp16) fit the 4MB L2.
// ---------------------------------------------------------------------------
#define PSTR 392   // fp16 K-stride: 2-way banks on B-frag ds_read_b128

__global__ __launch_bounds__(256) void pst_main(const float* __restrict__ xyzs,
                                                const float* __restrict__ w_d,
                                                const _Float16* __restrict__ wtH,
                                                const _Float16* __restrict__ G,
                                                const float* __restrict__ anchors,
                                                float* __restrict__ out_feat) {
  __shared__ union {
    float pxyz[NP * 3];                   // 24 KB   (frame loop)
    _Float16 sf[32][PSTR];                // 24.5 KB (GEMM phase)
  } u;
  __shared__ unsigned short nidx[32][KNN];    // 2 KB
  __shared__ float anc[32][3];

  // XCD swizzle: hw id h -> logical (h%8)*192 + h/8  (bijective, 1536%8==0)
  const int blk = (int)(blockIdx.x & 7) * 192 + (int)(blockIdx.x >> 3);
  const int mt = blk & 31;                // M/32 tiles
  const int bt = blk >> 5;                // b*6 + (t-1)
  const int b = bt / LFRM;
  const int t = bt % LFRM + 1;            // padded time index, 1..6
  const int tid = threadIdx.x;

  const float* asrc = anchors + ((size_t)bt * MP + (size_t)mt * 32) * 3;
  if (tid < 96) anc[tid / 3][tid % 3] = asrc[tid];
  __syncthreads();

  const int al = tid >> 3;                // anchor 0..31
  const int j = tid & 7;                  // 0..7 within anchor group
  const float ax = anc[al][0], ay = anc[al][1], az = anc[al][2];

  // wda = w_d·a in f32, then fp16 (error ~1e-3 vs threshold 6.1e-2)
  f16x4 wdah[4];
#pragma unroll
  for (int c4 = 0; c4 < 4; ++c4)
#pragma unroll
    for (int r = 0; r < 4; ++r) {
      int o = c4 * 32 + j * 4 + r;
      wdah[c4][r] = (_Float16)(w_d[o * 3 + 0] * ax + w_d[o * 3 + 1] * ay +
                               w_d[o * 3 + 2] * az);
    }
  const f16x4 hz = {(_Float16)0.f, (_Float16)0.f, (_Float16)0.f, (_Float16)0.f};

  const int lane = tid & 63, wv = tid >> 6;

  f16x4 hreg[3][4];                       // sf slices in regs (static idx only)

#pragma unroll
  for (int ii = 0; ii < 3; ++ii) {
    const int i = t - 1 + ii;             // padded frame 0..7

    if (i == 0 || i == LFRM + 1) {
      // pad frame: maxG := 0 -> sf = relu(-wda)
#pragma unroll
      for (int c4 = 0; c4 < 4; ++c4)
        hreg[ii][c4] = h4max(hz - wdah[c4], hz);
    } else {
      const int f2i = i - 1;
      const float* fxyz = xyzs + (size_t)(b * LFRM + f2i) * NP * 3;
      __syncthreads();                    // all waves done with prev pxyz
      for (int q = tid; q < NP * 3; q += 256) u.pxyz[q] = fxyz[q];
      __syncthreads();

      // ---- ball query: first KNN in-radius indices, in index order ----
      for (int aa = 0; aa < 8; ++aa) {
        const int a = wv * 8 + aa;
        const float qx = anc[a][0], qy = anc[a][1], qz = anc[a][2];
        int total = 0;
        int fillidx = 0;
        for (int ch = 0; ch < NP / 64; ++ch) {
          const int p = ch * 64 + lane;
          float d2;
          {
#pragma clang fp contract(off)
            float dx = qx - u.pxyz[p * 3 + 0];
            float dy = qy - u.pxyz[p * 3 + 1];
            float dz = qz - u.pxyz[p * 3 + 2];
            d2 = dx * dx + dy * dy + dz * dz;
          }
          const bool inb = d2 < RAD2;
          const unsigned long long mk = __ballot(inb);
          if (mk != 0ull && total == 0)
            fillidx = ch * 64 + (int)__builtin_ctzll(mk);
          const int before = (int)__builtin_popcountll(mk & ((1ull << lane) - 1ull));
          const int slot = total + before;
          if (inb && slot < KNN) nidx[a][slot] = (unsigned short)p;
          total += (int)__builtin_popcountll(mk);
          if (total >= KNN) break;        // uniform across wave
        }
        const int nf = total < KNN ? total : KNN;
        if (lane < KNN - nf) nidx[a][nf + lane] = (unsigned short)fillidx;
      }
      // NO barrier: nidx[al] is written and read by the same wave.

      // ---- mid: fp16 max over gathered G rows (8B loads, monotone) ----
      const _Float16* gfr = G + (size_t)(b * LFRM + f2i) * NP * MIDC;
      f16x4 mh0 = {(_Float16)-6e4f, (_Float16)-6e4f, (_Float16)-6e4f, (_Float16)-6e4f};
      f16x4 mh1 = mh0, mh2 = mh0, mh3 = mh0;
#pragma unroll 4
      for (int k = 0; k < KNN; ++k) {
        const int p = nidx[al][k];
        const f16x4* row = (const f16x4*)(gfr + (size_t)p * MIDC);
        f16x4 v0 = row[j], v1 = row[8 + j], v2 = row[16 + j], v3 = row[24 + j];
        mh0 = h4max(mh0, v0);
        mh1 = h4max(mh1, v1);
        mh2 = h4max(mh2, v2);
        mh3 = h4max(mh3, v3);
      }
      hreg[ii][0] = h4max(mh0 - wdah[0], hz);
      hreg[ii][1] = h4max(mh1 - wdah[1], hz);
      hreg[ii][2] = h4max(mh2 - wdah[2], hz);
      hreg[ii][3] = h4max(mh3 - wdah[3], hz);
    }
  }

  // pxyz dead; repurpose the region for sf
  __syncthreads();
#pragma unroll
  for (int ii = 0; ii < 3; ++ii)
#pragma unroll
    for (int c4 = 0; c4 < 4; ++c4)
      *(f16x4*)&u.sf[al][ii * MIDC + c4 * 32 + j * 4] = hreg[ii][c4];
  __syncthreads();

  // ---- GEMM: wave wv owns M-tiles wv*4..wv*4+3 (out-ch), N-tiles 0..1 ----
  const int l16 = lane & 15, lq = lane >> 4;
  f32x4 accm[4][2];
#pragma unroll
  for (int q = 0; q < 4; ++q)
#pragma unroll
    for (int n2 = 0; n2 < 2; ++n2) accm[q][n2] = f32x4{0.f, 0.f, 0.f, 0.f};

  for (int kc = 0; kc < TKM / 32; ++kc) {
    f16x8 bfr[2];
#pragma unroll
    for (int n2 = 0; n2 < 2; ++n2)
      bfr[n2] = *(const f16x8*)&u.sf[n2 * 16 + l16][kc * 32 + lq * 8];
#pragma unroll
    for (int q = 0; q < 4; ++q) {
      const int row = (wv * 4 + q) * 16 + l16;
      const f16x8 afr = *(const f16x8*)&wtH[(size_t)row * TKM + kc * 32 + lq * 8];
      accm[q][0] = __builtin_amdgcn_mfma_f32_16x16x32_f16(afr, bfr[0], accm[q][0], 0, 0, 0);
      accm[q][1] = __builtin_amdgcn_mfma_f32_16x16x32_f16(afr, bfr[1], accm[q][1], 0, 0, 0);
    }
  }

  // epilogue: D row = out-ch offset lq*4+r, col = anchor l16 (m89 layout)
  float* ob = out_feat + (size_t)bt * OUTC * MP + (size_t)mt * 32;
#pragma unroll
  for (int q = 0; q < 4; ++q) {
    const int orow = (wv * 4 + q) * 16 + lq * 4;
#pragma unroll
    for (int n2 = 0; n2 < 2; ++n2)
#pragma unroll
      for (int r = 0; r < 4; ++r)
        ob[(size_t)(orow + r) * MP + n2 * 16 + l16] = accm[q][n2][r];
  }
}

// ---------------------------------------------------------------------------
extern "C" void kernel_launch(void* const* d_in, const int* in_sizes, int n_in,
                              void* d_out, int out_size, void* d_ws, size_t ws_size,
                              hipStream_t stream) {
  const float* xyzs = (const float*)d_in[0];
  const float* features = (const float*)d_in[1];
  const float* w_d = (const float*)d_in[2];
  const float* w_f = (const float*)d_in[3];
  const float* w_t = (const float*)d_in[4];

  float* out = (float*)d_out;
  float* out_xyz = out;                                        // (B,6,M,3)
  float* out_feat = out + (size_t)BATCH * LFRM * MP * 3;       // (B,6,256,M)
  _Float16* G = (_Float16*)d_ws;                               // (B,L,N,128) fp16
  _Float16* wtH = G + (size_t)BATCH * LFRM * NP * MIDC;        // (256,384) fp16

  hipLaunchKernelGGL(fps_ftrans_kernel,
                     dim3(FPS_BLOCKS + WT_BLOCKS + FT_BLOCKS), dim3(256),
                     0, stream, xyzs, features, w_f, w_d, w_t, out_xyz, G, wtH);
  hipLaunchKernelGGL(pst_main, dim3(BATCH * LFRM * (MP / 32)), dim3(256), 0,
                     stream, xyzs, w_d, wtH, G, out_xyz, out_feat);
}

// Round 12
// 569.145 us; speedup vs baseline: 1.2369x; 1.2369x over previous
//
#include <hip/hip_runtime.h>

#define BATCH 8
#define LFRM  6
#define NP    2048
#define MP    1024
#define CIN   64
#define MIDC  128
#define OUTC  256
#define TKM   384
#define KNN   32
#define RAD2  0.25f

#define FPS_BLOCKS (BATCH * LFRM)
#define WT_BLOCKS  ((OUTC * TKM) / (256 * 4))   // 96
#define FT_BLOCKS  (BATCH * LFRM * (NP / 64))
#define WFS 132   // wfT row stride: 16B-aligned rows (528B) for b128 reads

typedef float f2 __attribute__((ext_vector_type(2)));
typedef float f32x4 __attribute__((ext_vector_type(4)));
typedef _Float16 f16x8 __attribute__((ext_vector_type(8)));
typedef _Float16 f16x4 __attribute__((ext_vector_type(4)));

// LDS union: fps needs 32.9KB; ftrans needs ~51.3KB.
union SharedU {
  struct {
    float4 pts[NP];                    // 32 KB, [x,y,z,pad]
    unsigned long long wk[2][4];       // parity-double-buffered wave keys
  } fps;
  struct {
    float ftile[CIN][64];              // 16 KB
    float wfT[CIN][WFS];               // 33 KB  [c][o], 16B-aligned rows
    float xt[64], yt[64], zt[64];      // point coords of this tile
    float wdl[MIDC * 3];               // w_d staged
  } ft;
};

__device__ __forceinline__ uint64_t kmax64(uint64_t a, uint64_t b) {
  return a > b ? a : b;
}
template <int CTRL>
__device__ __forceinline__ uint64_t key_dpp(uint64_t k) {
  int lo = __builtin_amdgcn_update_dpp((int)(uint32_t)k, (int)(uint32_t)k,
                                       CTRL, 0xF, 0xF, false);
  int hi = __builtin_amdgcn_update_dpp((int)(uint32_t)(k >> 32),
                                       (int)(uint32_t)(k >> 32),
                                       CTRL, 0xF, 0xF, false);
  return ((uint64_t)(uint32_t)hi << 32) | (uint32_t)lo;
}

__device__ __forceinline__ f16x4 h4max(f16x4 a, f16x4 b) {
  f16x4 r;
  r[0] = a[0] > b[0] ? a[0] : b[0];
  r[1] = a[1] > b[1] ? a[1] : b[1];
  r[2] = a[2] > b[2] ? a[2] : b[2];
  r[3] = a[3] > b[3] ? a[3] : b[3];
  return r;
}

// ---------------------------------------------------------------------------
// FPS: r10's version VERBATIM — CONVERGED, do not modify. (461us measured in
// r8 and r10; r9's swz-revert and r11's coord-publish were both slower.)
// Key = (f32bits(dist)<<32) | ~idx; max-key == numpy first-occurrence argmax.
// ---------------------------------------------------------------------------
__device__ __forceinline__ void fps_path(const float* __restrict__ xyzs,
                                         float* __restrict__ out_xyz,
                                         SharedU* sh) {
#pragma clang fp contract(off)
  const int bt = blockIdx.x;              // b*6 + frame
  const int tid = threadIdx.x;
  const int lane = tid & 63, wv = tid >> 6;
  const float* src = xyzs + (size_t)bt * NP * 3;

  for (int q = tid; q < NP; q += 256)
    sh->fps.pts[q] = make_float4(src[q * 3 + 0], src[q * 3 + 1], src[q * 3 + 2], 0.f);
  __syncthreads();

  // wave wv owns slots [wv*8, wv*8+8); point p = slot*64 + lane
  f2 px[4], py[4], pz[4], dist[4];
#pragma unroll
  for (int u = 0; u < 4; ++u) {
    float4 a = sh->fps.pts[(wv * 8 + 2 * u) * 64 + lane];
    float4 b = sh->fps.pts[(wv * 8 + 2 * u + 1) * 64 + lane];
    px[u] = f2{a.x, b.x};
    py[u] = f2{a.y, b.y};
    pz[u] = f2{a.z, b.z};
    dist[u] = f2{1e10f, 1e10f};
  }

  float4 p0 = sh->fps.pts[0];
  float fx = p0.x, fy = p0.y, fz = p0.z;  // far = 0 initially
  float* dst = out_xyz + (size_t)bt * MP * 3;

  for (int it = 0; it < MP; ++it) {
    if (tid == 0) {                       // emit current far point
      dst[it * 3 + 0] = fx;
      dst[it * 3 + 1] = fy;
      dst[it * 3 + 2] = fz;
    }
    const f2 fx2 = {fx, fx}, fy2 = {fy, fy}, fz2 = {fz, fz};
    float bv = -1.0f;
    int bsu = 0;
#pragma unroll
    for (int u = 0; u < 4; ++u) {
      f2 dx = px[u] - fx2;
      f2 dy = py[u] - fy2;
      f2 dz = pz[u] - fz2;
      f2 m = dx * dx;                     // contract off: ((dx^2+dy^2)+dz^2)
      m = m + dy * dy;
      m = m + dz * dz;
      f2 nd = __builtin_elementwise_min(dist[u], m);
      dist[u] = nd;
      bool cx = nd.x > bv;                // first-occurrence: strict >
      bv = cx ? nd.x : bv;
      bsu = cx ? 2 * u : bsu;
      bool cy = nd.y > bv;
      bv = cy ? nd.y : bv;
      bsu = cy ? 2 * u + 1 : bsu;
    }
    const uint32_t p = (uint32_t)(((wv * 8 + bsu) << 6) | lane);
    uint64_t key = ((uint64_t)__float_as_uint(bv) << 32) | (uint32_t)(~p);
    key = kmax64(key, key_dpp<0x121>(key));   // row_ror:1
    key = kmax64(key, key_dpp<0x122>(key));   // row_ror:2
    key = kmax64(key, key_dpp<0x124>(key));   // row_ror:4
    key = kmax64(key, key_dpp<0x128>(key));   // row_ror:8  -> row max
    key = kmax64(key, key_dpp<0x142>(key));   // row_bcast15
    key = kmax64(key, key_dpp<0x143>(key));   // row_bcast31: lane63 = wave max

    const int par = it & 1;
    if (lane == 63) sh->fps.wk[par][wv] = key;
    __syncthreads();
    uint64_t k0 = kmax64(sh->fps.wk[par][0], sh->fps.wk[par][1]);
    uint64_t k1 = kmax64(sh->fps.wk[par][2], sh->fps.wk[par][3]);
    uint64_t kg = kmax64(k0, k1);
    const uint32_t wp = ~(uint32_t)kg;        // winner point index
    float4 w = sh->fps.pts[wp];               // uniform -> broadcast read
    fx = w.x; fy = w.y; fz = w.z;
  }
}

// ---------------------------------------------------------------------------
// wt: one-time fp16 conversion of w_t.
// ---------------------------------------------------------------------------
__device__ __forceinline__ void wt_path(const float* __restrict__ w_t,
                                        _Float16* __restrict__ wtH) {
  const int blk = blockIdx.x - FPS_BLOCKS;
  const int idx = (blk * 256 + (int)threadIdx.x) * 4;
  const float4 v = *(const float4*)&w_t[idx];
  f16x4 h;
  h[0] = (_Float16)v.x; h[1] = (_Float16)v.y;
  h[2] = (_Float16)v.z; h[3] = (_Float16)v.w;
  *(f16x4*)&wtH[idx] = h;
}

// ---------------------------------------------------------------------------
// ftrans: G[b,l,n,o] = sum_c w_f[o,c]*features[b,l,c,n] + w_d[o]·xyz[b,l,n]
// Register-blocked 4o x 8n per thread; fp16 G output (max is monotone).
// ---------------------------------------------------------------------------
__device__ __forceinline__ void ftrans_path(const float* __restrict__ features,
                                            const float* __restrict__ w_f,
                                            const float* __restrict__ w_d,
                                            const float* __restrict__ xyzs,
                                            _Float16* __restrict__ G,
                                            SharedU* sh) {
  const int blk = blockIdx.x - FPS_BLOCKS - WT_BLOCKS;
  const int ntile = blk & 31;             // N/64 tiles
  const int bl = blk >> 5;                // b*L + l
  const int tid = threadIdx.x;

  const float* fsrc = features + (size_t)bl * CIN * NP + (size_t)ntile * 64;
  for (int idx = tid; idx < CIN * 64; idx += 256) {
    int c = idx >> 6, n = idx & 63;
    sh->ft.ftile[c][n] = fsrc[(size_t)c * NP + n];
  }
  for (int idx = tid; idx < CIN * MIDC; idx += 256) {
    int c = idx & 63, o = idx >> 6;       // coalesced w_f row reads
    sh->ft.wfT[c][o] = w_f[o * CIN + c];
  }
  if (tid < 64) {
    const float* xs = xyzs + ((size_t)bl * NP + (size_t)ntile * 64 + tid) * 3;
    sh->ft.xt[tid] = xs[0];
    sh->ft.yt[tid] = xs[1];
    sh->ft.zt[tid] = xs[2];
  }
  for (int idx = tid; idx < MIDC * 3; idx += 256) sh->ft.wdl[idx] = w_d[idx];
  __syncthreads();

  const int op = tid & 31;                // o base = op*4 (coalesced stores)
  const int ng = tid >> 5;                // n base = ng*8 (broadcast ftile)
  const int ob = op * 4;
  const int nb = ng * 8;

  float acc[4][8];                        // all index loops fully unrolled
#pragma unroll
  for (int oo = 0; oo < 4; ++oo) {
    const float w0 = sh->ft.wdl[(ob + oo) * 3 + 0];
    const float w1 = sh->ft.wdl[(ob + oo) * 3 + 1];
    const float w2 = sh->ft.wdl[(ob + oo) * 3 + 2];
#pragma unroll
    for (int j = 0; j < 8; ++j)
      acc[oo][j] = w0 * sh->ft.xt[nb + j] + w1 * sh->ft.yt[nb + j] +
                   w2 * sh->ft.zt[nb + j];
  }

#pragma unroll 4
  for (int c = 0; c < CIN; ++c) {
    const float4 wq = *(const float4*)&sh->ft.wfT[c][ob];
    const float4 fA = *(const float4*)&sh->ft.ftile[c][nb];
    const float4 fB = *(const float4*)&sh->ft.ftile[c][nb + 4];
    const float wo[4] = {wq.x, wq.y, wq.z, wq.w};
    const float fv[8] = {fA.x, fA.y, fA.z, fA.w, fB.x, fB.y, fB.z, fB.w};
#pragma unroll
    for (int oo = 0; oo < 4; ++oo)
#pragma unroll
      for (int j = 0; j < 8; ++j)
        acc[oo][j] += wo[oo] * fv[j];
  }

  _Float16* dstp = G + ((size_t)bl * NP + (size_t)ntile * 64) * MIDC;
#pragma unroll
  for (int j = 0; j < 8; ++j) {
    f16x4 v;
    v[0] = (_Float16)acc[0][j]; v[1] = (_Float16)acc[1][j];
    v[2] = (_Float16)acc[2][j]; v[3] = (_Float16)acc[3][j];
    *(f16x4*)&dstp[(size_t)(nb + j) * MIDC + ob] = v;
  }
}

__global__ __launch_bounds__(256, 1) void fps_ftrans_kernel(
    const float* __restrict__ xyzs, const float* __restrict__ features,
    const float* __restrict__ w_f, const float* __restrict__ w_d,
    const float* __restrict__ w_t, float* __restrict__ out_xyz,
    _Float16* __restrict__ G, _Float16* __restrict__ wtH) {
  __shared__ SharedU sh;
  if (blockIdx.x < FPS_BLOCKS) {
    fps_path(xyzs, out_xyz, &sh);
    return;
  }
  if (blockIdx.x < FPS_BLOCKS + WT_BLOCKS) {
    wt_path(w_t, wtH);
    return;
  }
  ftrans_path(features, w_f, w_d, xyzs, G, &sh);
}

// ---------------------------------------------------------------------------
// pst_main: ball query + fp16 gathered max-pool of G + fp16 MFMA w_t GEMM.
// r10 structure + XCD-bijective block swizzle (1536 % 8 == 0): each XCD
// hosts the 6 consecutive bt of one batch -> 6 G-frames (3MB) fit 4MB L2.
// ---------------------------------------------------------------------------
#define PSTR 392   // fp16 K-stride: 2-way banks on B-frag ds_read_b128

__global__ __launch_bounds__(256) void pst_main(const float* __restrict__ xyzs,
                                                const float* __restrict__ w_d,
                                                const _Float16* __restrict__ wtH,
                                                const _Float16* __restrict__ G,
                                                const float* __restrict__ anchors,
                                                float* __restrict__ out_feat) {
  __shared__ union {
    float pxyz[NP * 3];                   // 24 KB   (frame loop)
    _Float16 sf[32][PSTR];                // 24.5 KB (GEMM phase)
  } u;
  __shared__ unsigned short nidx[32][KNN];    // 2 KB
  __shared__ float anc[32][3];

  // XCD swizzle: hw id h -> logical (h%8)*192 + h/8  (bijective, 1536%8==0)
  const int blk = (int)(blockIdx.x & 7) * 192 + (int)(blockIdx.x >> 3);
  const int mt = blk & 31;                // M/32 tiles
  const int bt = blk >> 5;                // b*6 + (t-1)
  const int b = bt / LFRM;
  const int t = bt % LFRM + 1;            // padded time index, 1..6
  const int tid = threadIdx.x;

  const float* asrc = anchors + ((size_t)bt * MP + (size_t)mt * 32) * 3;
  if (tid < 96) anc[tid / 3][tid % 3] = asrc[tid];
  __syncthreads();

  const int al = tid >> 3;                // anchor 0..31
  const int j = tid & 7;                  // 0..7 within anchor group
  const float ax = anc[al][0], ay = anc[al][1], az = anc[al][2];

  // wda = w_d·a in f32, then fp16 (error ~1e-3 vs threshold 6.1e-2)
  f16x4 wdah[4];
#pragma unroll
  for (int c4 = 0; c4 < 4; ++c4)
#pragma unroll
    for (int r = 0; r < 4; ++r) {
      int o = c4 * 32 + j * 4 + r;
      wdah[c4][r] = (_Float16)(w_d[o * 3 + 0] * ax + w_d[o * 3 + 1] * ay +
                               w_d[o * 3 + 2] * az);
    }
  const f16x4 hz = {(_Float16)0.f, (_Float16)0.f, (_Float16)0.f, (_Float16)0.f};

  const int lane = tid & 63, wv = tid >> 6;

  f16x4 hreg[3][4];                       // sf slices in regs (static idx only)

#pragma unroll
  for (int ii = 0; ii < 3; ++ii) {
    const int i = t - 1 + ii;             // padded frame 0..7

    if (i == 0 || i == LFRM + 1) {
      // pad frame: maxG := 0 -> sf = relu(-wda)
#pragma unroll
      for (int c4 = 0; c4 < 4; ++c4)
        hreg[ii][c4] = h4max(hz - wdah[c4], hz);
    } else {
      const int f2i = i - 1;
      const float* fxyz = xyzs + (size_t)(b * LFRM + f2i) * NP * 3;
      __syncthreads();                    // all waves done with prev pxyz
      for (int q = tid; q < NP * 3; q += 256) u.pxyz[q] = fxyz[q];
      __syncthreads();

      // ---- ball query: first KNN in-radius indices, in index order ----
      for (int aa = 0; aa < 8; ++aa) {
        const int a = wv * 8 + aa;
        const float qx = anc[a][0], qy = anc[a][1], qz = anc[a][2];
        int total = 0;
        int fillidx = 0;
        for (int ch = 0; ch < NP / 64; ++ch) {
          const int p = ch * 64 + lane;
          float d2;
          {
#pragma clang fp contract(off)
            float dx = qx - u.pxyz[p * 3 + 0];
            float dy = qy - u.pxyz[p * 3 + 1];
            float dz = qz - u.pxyz[p * 3 + 2];
            d2 = dx * dx + dy * dy + dz * dz;
          }
          const bool inb = d2 < RAD2;
          const unsigned long long mk = __ballot(inb);
          if (mk != 0ull && total == 0)
            fillidx = ch * 64 + (int)__builtin_ctzll(mk);
          const int before = (int)__builtin_popcountll(mk & ((1ull << lane) - 1ull));
          const int slot = total + before;
          if (inb && slot < KNN) nidx[a][slot] = (unsigned short)p;
          total += (int)__builtin_popcountll(mk);
          if (total >= KNN) break;        // uniform across wave
        }
        const int nf = total < KNN ? total : KNN;
        if (lane < KNN - nf) nidx[a][nf + lane] = (unsigned short)fillidx;
      }
      // NO barrier: nidx[al] is written and read by the same wave.

      // ---- mid: fp16 max over gathered G rows (8B loads, monotone) ----
      const _Float16* gfr = G + (size_t)(b * LFRM + f2i) * NP * MIDC;
      f16x4 mh0 = {(_Float16)-6e4f, (_Float16)-6e4f, (_Float16)-6e4f, (_Float16)-6e4f};
      f16x4 mh1 = mh0, mh2 = mh0, mh3 = mh0;
#pragma unroll 4
      for (int k = 0; k < KNN; ++k) {
        const int p = nidx[al][k];
        const f16x4* row = (const f16x4*)(gfr + (size_t)p * MIDC);
        f16x4 v0 = row[j], v1 = row[8 + j], v2 = row[16 + j], v3 = row[24 + j];
        mh0 = h4max(mh0, v0);
        mh1 = h4max(mh1, v1);
        mh2 = h4max(mh2, v2);
        mh3 = h4max(mh3, v3);
      }
      hreg[ii][0] = h4max(mh0 - wdah[0], hz);
      hreg[ii][1] = h4max(mh1 - wdah[1], hz);
      hreg[ii][2] = h4max(mh2 - wdah[2], hz);
      hreg[ii][3] = h4max(mh3 - wdah[3], hz);
    }
  }

  // pxyz dead; repurpose the region for sf
  __syncthreads();
#pragma unroll
  for (int ii = 0; ii < 3; ++ii)
#pragma unroll
    for (int c4 = 0; c4 < 4; ++c4)
      *(f16x4*)&u.sf[al][ii * MIDC + c4 * 32 + j * 4] = hreg[ii][c4];
  __syncthreads();

  // ---- GEMM: wave wv owns M-tiles wv*4..wv*4+3 (out-ch), N-tiles 0..1 ----
  const int l16 = lane & 15, lq = lane >> 4;
  f32x4 accm[4][2];
#pragma unroll
  for (int q = 0; q < 4; ++q)
#pragma unroll
    for (int n2 = 0; n2 < 2; ++n2) accm[q][n2] = f32x4{0.f, 0.f, 0.f, 0.f};

  for (int kc = 0; kc < TKM / 32; ++kc) {
    f16x8 bfr[2];
#pragma unroll
    for (int n2 = 0; n2 < 2; ++n2)
      bfr[n2] = *(const f16x8*)&u.sf[n2 * 16 + l16][kc * 32 + lq * 8];
#pragma unroll
    for (int q = 0; q < 4; ++q) {
      const int row = (wv * 4 + q) * 16 + l16;
      const f16x8 afr = *(const f16x8*)&wtH[(size_t)row * TKM + kc * 32 + lq * 8];
      accm[q][0] = __builtin_amdgcn_mfma_f32_16x16x32_f16(afr, bfr[0], accm[q][0], 0, 0, 0);
      accm[q][1] = __builtin_amdgcn_mfma_f32_16x16x32_f16(afr, bfr[1], accm[q][1], 0, 0, 0);
    }
  }

  // epilogue: D row = out-ch offset lq*4+r, col = anchor l16 (m89 layout)
  float* ob = out_feat + (size_t)bt * OUTC * MP + (size_t)mt * 32;
#pragma unroll
  for (int q = 0; q < 4; ++q) {
    const int orow = (wv * 4 + q) * 16 + lq * 4;
#pragma unroll
    for (int n2 = 0; n2 < 2; ++n2)
#pragma unroll
      for (int r = 0; r < 4; ++r)
        ob[(size_t)(orow + r) * MP + n2 * 16 + l16] = accm[q][n2][r];
  }
}

// ---------------------------------------------------------------------------
extern "C" void kernel_launch(void* const* d_in, const int* in_sizes, int n_in,
                              void* d_out, int out_size, void* d_ws, size_t ws_size,
                              hipStream_t stream) {
  const float* xyzs = (const float*)d_in[0];
  const float* features = (const float*)d_in[1];
  const float* w_d = (const float*)d_in[2];
  const float* w_f = (const float*)d_in[3];
  const float* w_t = (const float*)d_in[4];

  float* out = (float*)d_out;
  float* out_xyz = out;                                        // (B,6,M,3)
  float* out_feat = out + (size_t)BATCH * LFRM * MP * 3;       // (B,6,256,M)
  _Float16* G = (_Float16*)d_ws;                               // (B,L,N,128) fp16
  _Float16* wtH = G + (size_t)BATCH * LFRM * NP * MIDC;        // (256,384) fp16

  hipLaunchKernelGGL(fps_ftrans_kernel,
                     dim3(FPS_BLOCKS + WT_BLOCKS + FT_BLOCKS), dim3(256),
                     0, stream, xyzs, features, w_f, w_d, w_t, out_xyz, G, wtH);
  hipLaunchKernelGGL(pst_main, dim3(BATCH * LFRM * (MP / 32)), dim3(256), 0,
                     stream, xyzs, w_d, wtH, G, out_xyz, out_feat);
}